// Round 9
// baseline (54.288 us; speedup 1.0000x reference)
//
#include <hip/hip_runtime.h>
#include <hip/hip_bf16.h>

#define NN 1024
#define DD 128
#define KK 16
#define CAP 128

typedef __attribute__((ext_vector_type(4))) float f32x4;
typedef __attribute__((ext_vector_type(8))) short bf16x8;
typedef __attribute__((ext_vector_type(4))) unsigned int u32x4;

static __device__ __forceinline__ unsigned short f2bf(float x) {
  union { __hip_bfloat16 h; unsigned short u; } v;
  v.h = __float2bfloat16(x);
  return v.u;
}
static __device__ __forceinline__ float bf2f(unsigned short u) {
  union { unsigned int ui; float f; } v;
  v.ui = ((unsigned int)u) << 16;
  return v.f;
}

// ---------------------------------------------------------------------------
// Kernel 1: neighbor lists (wave ballot scan) + per-edge RBF in bf16.
// Tail: casts embed/w1/w2 -> bf16; block 272 builds wfT[3][128][32] (k-padded).
// ---------------------------------------------------------------------------
__global__ __launch_bounds__(256) void edge_build(
    const float* __restrict__ r, const float* __restrict__ embed,
    const float* __restrict__ w1, const float* __restrict__ w2,
    const float* __restrict__ wfilt,
    int* __restrict__ cnt, int* __restrict__ nidx,
    unsigned short* __restrict__ edata16,
    unsigned short* __restrict__ hb16, unsigned short* __restrict__ w1b,
    unsigned short* __restrict__ w2b, unsigned short* __restrict__ wfT)
{
  int b = blockIdx.x, tid = threadIdx.x;
  if (b < 256) {
    __shared__ float Rs[NN][3];
    for (int idx = tid; idx < NN * 3; idx += 256) ((float*)Rs)[idx] = r[idx];
    __syncthreads();
    int wv = tid >> 6, lane = tid & 63;
    int i = b * 4 + wv;
    float xi = Rs[i][0], yi = Rs[i][1], zi = Rs[i][2];
    int base = 0;
    for (int it = 0; it < 16; ++it) {
      int j = it * 64 + lane;
      float dx = xi - Rs[j][0], dy = yi - Rs[j][1], dz = zi - Rs[j][2];
      float d2 = dx * dx + dy * dy + dz * dz;
      bool on = (j != i) && (d2 < 4.0f);
      unsigned long long mask = __ballot(on);
      int slot = base + (int)__popcll(mask & ((1ull << lane) - 1ull));
      if (on && slot < CAP) {
        float dist = sqrtf(d2);
        float w  = 0.5f * (__cosf(1.57079632679f * dist) + 1.0f);  // cos(pi*d/2)
        float E0 = __expf(-10.0f * d2);
        float q  = __expf(2.66666667f * dist);      // exp(20*(2/15)*d)
        float u  = __expf(-0.17777778f);            // exp(-10*(2/15)^2)
        float u2 = u * u;
        float p = 1.0f, c = 1.0f, s = u;
        float vals[KK];
        #pragma unroll
        for (int k = 0; k < KK; ++k) {
          vals[k] = w * (E0 * p) * c;   // = w * exp(-10*(dist - k*2/15)^2)
          p *= q; c *= s; s *= u2;
        }
        nidx[i * CAP + slot] = j;
        unsigned short* dst = edata16 + ((size_t)i * CAP + slot) * KK;
        #pragma unroll
        for (int k = 0; k < KK; ++k) dst[k] = f2bf(vals[k]);
      }
      base += (int)__popcll(mask);
    }
    if (lane == 0) cnt[i] = (base < CAP) ? base : CAP;
  } else if (b < 272) {
    // straight casts: embed (131072) | w1 (49152) | w2 (49152)
    int gt = (b - 256) * 256 + tid;
    for (int f = gt; f < 229376; f += 4096) {
      if (f < 131072)      hb16[f]          = f2bf(embed[f]);
      else if (f < 180224) w1b[f - 131072]  = f2bf(w1[f - 131072]);
      else                 w2b[f - 180224]  = f2bf(w2[f - 180224]);
    }
  } else {
    // wfT[l][d][kk]: transpose of wfilt[l][k][d], k zero-padded 16->32
    for (int e = tid; e < 3 * 128 * 32; e += 256) {
      int l = e >> 12, rem = e & 4095, dd = rem >> 5, kk = rem & 31;
      wfT[e] = (kk < KK) ? f2bf(wfilt[l * 2048 + kk * 128 + dd])
                         : (unsigned short)0;
    }
  }
}

// ---------------------------------------------------------------------------
// Kernel 2 (per layer): one WG per node. SINGLE 128-row panel (CAP=128):
//   nxs: neighbor indices LDS-preloaded; stage Hs (128 neighbor h rows) +
//   As (edge RBF, k-padded), zero-padded past cn.
//   F = e @ wfT via 16x mfma_f32_16x16x32_bf16 (r8-verified fragment layout),
//   PV: agg_d += F[s][d] * Hs[s][d], shfl row-reduce.
// Then node MLP (r8-verified VALU body) + residual.
// ---------------------------------------------------------------------------
__global__ __launch_bounds__(256) void layer_fused(
    const int* __restrict__ cnt, const int* __restrict__ nidx,
    const unsigned short* __restrict__ edata16,
    const unsigned short* __restrict__ hb16in,
    const float* __restrict__ hprev,
    const unsigned short* __restrict__ wfTL,      // [128][32] bf16 this layer
    const unsigned short* __restrict__ w1b, const float* __restrict__ b1,
    const unsigned short* __restrict__ w2b, const float* __restrict__ b2,
    float* __restrict__ hnext,
    unsigned short* __restrict__ hb16out,
    float* __restrict__ outf)
{
  __shared__ unsigned short Hs[128][136];  // 34.8 KB neighbor h rows
  __shared__ unsigned short As[128][40];   // 10.2 KB edge RBF rows (k-padded)
  __shared__ int   nxs[128];
  __shared__ float xv[128];
  __shared__ float yv[128];
  __shared__ float part4[4][128];

  int i = blockIdx.x, tid = threadIdx.x;
  int w = tid >> 6, lane = tid & 63;
  int lg = lane >> 4, l16 = lane & 15;
  int cn = cnt[i];

  // B fragments (layer-constant): nt in {0,1}, N-row d = (w*2+nt)*16 + l16
  bf16x8 bfr[2];
  #pragma unroll
  for (int nt = 0; nt < 2; ++nt) {
    int d = (w * 2 + nt) * 16 + l16;
    bfr[nt] = *(const bf16x8*)(wfTL + d * 32 + lg * 8);
  }

  if (tid < 128) nxs[tid] = nidx[i * CAP + tid];
  __syncthreads();

  // stage Hs: 128 rows x 16 dwordx4 chunks (8 per thread)
  #pragma unroll
  for (int it = 0; it < 8; ++it) {
    int c = tid + it * 256;
    int row = c >> 4, ch = c & 15;
    u32x4 v = {0u, 0u, 0u, 0u};
    if (row < cn) {
      int j = nxs[row];
      v = *(const u32x4*)(hb16in + (size_t)j * DD + ch * 8);
    }
    *(u32x4*)(&Hs[row][ch * 8]) = v;
  }
  // stage As: 128 rows x 4 chunks (2 data + 2 zero-pad), 2 per thread
  #pragma unroll
  for (int it = 0; it < 2; ++it) {
    int c = tid + it * 256;
    int row = c >> 2, ch = c & 3;
    u32x4 v = {0u, 0u, 0u, 0u};
    if (row < cn && ch < 2)
      v = *(const u32x4*)(edata16 + ((size_t)i * CAP + row) * KK + ch * 8);
    *(u32x4*)(&As[row][ch * 8]) = v;
  }
  __syncthreads();

  // F = e @ wfT : acc[mt][nt], C[row=edge s][col=d]; 16 MFMA
  f32x4 acc[8][2];
  #pragma unroll
  for (int mt = 0; mt < 8; ++mt)
    #pragma unroll
    for (int nt = 0; nt < 2; ++nt)
      acc[mt][nt] = (f32x4){0.f, 0.f, 0.f, 0.f};
  #pragma unroll
  for (int mt = 0; mt < 8; ++mt) {
    bf16x8 af = *(const bf16x8*)(&As[mt * 16 + l16][lg * 8]);
    #pragma unroll
    for (int nt = 0; nt < 2; ++nt)
      acc[mt][nt] = __builtin_amdgcn_mfma_f32_16x16x32_bf16(
          af, bfr[nt], acc[mt][nt], 0, 0, 0);
  }

  // PV: agg_d += F[s][d] * h[s][d]   (s = mt*16 + lg*4 + rr)
  float aggv0 = 0.f, aggv1 = 0.f;
  #pragma unroll
  for (int nt = 0; nt < 2; ++nt) {
    int d = (w * 2 + nt) * 16 + l16;
    float s = 0.f;
    #pragma unroll
    for (int mt = 0; mt < 8; ++mt)
      #pragma unroll
      for (int rr = 0; rr < 4; ++rr)
        s += acc[mt][nt][rr] * bf2f(Hs[mt * 16 + lg * 4 + rr][d]);
    if (nt == 0) aggv0 += s; else aggv1 += s;
  }
  aggv0 += __shfl_xor(aggv0, 16, 64);
  aggv0 += __shfl_xor(aggv0, 32, 64);
  aggv1 += __shfl_xor(aggv1, 16, 64);
  aggv1 += __shfl_xor(aggv1, 32, 64);
  if (lg == 0) {
    xv[(w * 2 + 0) * 16 + l16] = aggv0;
    xv[(w * 2 + 1) * 16 + l16] = aggv1;
  }
  __syncthreads();

  // ---------------- node MLP (r8-verified) ----------------
  int dp = tid & 63, pp = tid >> 6;
  float o1a = 0.f, o1b = 0.f;
  #pragma unroll 8
  for (int q = 0; q < 32; ++q) {
    int di = pp * 32 + q;
    float x = xv[di];
    unsigned int wp = *(const unsigned int*)(w1b + di * DD + dp * 2);
    o1a += x * bf2f((unsigned short)(wp & 0xffffu));
    o1b += x * bf2f((unsigned short)(wp >> 16));
  }
  part4[pp][dp * 2] = o1a;
  part4[pp][dp * 2 + 1] = o1b;
  __syncthreads();
  if (tid < 128) {
    float x = part4[0][tid] + part4[1][tid] + part4[2][tid] + part4[3][tid] + b1[tid];
    yv[tid] = x / (1.f + __expf(-x));   // silu
  }
  __syncthreads();
  float o2a = 0.f, o2b = 0.f;
  #pragma unroll 8
  for (int q = 0; q < 32; ++q) {
    int di = pp * 32 + q;
    float yy = yv[di];
    unsigned int wp = *(const unsigned int*)(w2b + di * DD + dp * 2);
    o2a += yy * bf2f((unsigned short)(wp & 0xffffu));
    o2b += yy * bf2f((unsigned short)(wp >> 16));
  }
  part4[pp][dp * 2] = o2a;
  part4[pp][dp * 2 + 1] = o2b;
  __syncthreads();
  if (tid < 128) {
    float v = part4[0][tid] + part4[1][tid] + part4[2][tid] + part4[3][tid]
              + b2[tid] + hprev[(size_t)i * DD + tid];
    if (outf) {
      outf[(size_t)i * DD + tid] = v;
    } else {
      hnext[(size_t)i * DD + tid]   = v;
      hb16out[(size_t)i * DD + tid] = f2bf(v);
    }
  }
}

// ---------------------------------------------------------------------------
extern "C" void kernel_launch(void* const* d_in, const int* in_sizes, int n_in,
                              void* d_out, int out_size, void* d_ws, size_t ws_size,
                              hipStream_t stream) {
  (void)in_sizes; (void)n_in; (void)out_size; (void)ws_size;
  const float* r     = (const float*)d_in[0];
  const float* embed = (const float*)d_in[1];
  const float* wfilt = (const float*)d_in[2];
  const float* w1    = (const float*)d_in[3];
  const float* b1    = (const float*)d_in[4];
  const float* w2    = (const float*)d_in[5];
  const float* b2    = (const float*)d_in[6];

  char* ws = (char*)d_ws;
  size_t off = 0;
  auto alloc = [&](size_t bytes) {
    void* p = ws + off; off += (bytes + 255) & ~(size_t)255; return p;
  };
  unsigned short* EDATA = (unsigned short*)alloc((size_t)NN * CAP * KK * 2); // 4.2 MB
  int*            NIDX  = (int*)alloc((size_t)NN * CAP * 4);                 // 512 KB
  int*            CNT   = (int*)alloc((size_t)NN * 4);
  unsigned short* HB16A = (unsigned short*)alloc((size_t)NN * DD * 2);
  unsigned short* HB16B = (unsigned short*)alloc((size_t)NN * DD * 2);
  unsigned short* W1B   = (unsigned short*)alloc((size_t)3 * DD * DD * 2);
  unsigned short* W2B   = (unsigned short*)alloc((size_t)3 * DD * DD * 2);
  unsigned short* WFT   = (unsigned short*)alloc((size_t)3 * DD * 32 * 2);
  float*          HB    = (float*)alloc((size_t)NN * DD * 4);

  edge_build<<<273, 256, 0, stream>>>(r, embed, w1, w2, wfilt,
                                      CNT, NIDX, EDATA, HB16A, W1B, W2B, WFT);

  const float* hp = embed;
  for (int l = 0; l < 3; ++l) {
    bool fin = (l == 2);
    const unsigned short* in16  = (l == 1) ? HB16B : HB16A;
    unsigned short*       out16 = (l == 0) ? HB16B : HB16A;
    layer_fused<<<NN, 256, 0, stream>>>(
        CNT, NIDX, EDATA, in16, hp,
        WFT + (size_t)l * DD * 32,
        W1B + (size_t)l * DD * DD, b1 + (size_t)l * DD,
        W2B + (size_t)l * DD * DD, b2 + (size_t)l * DD,
        fin ? nullptr : HB, fin ? nullptr : out16,
        fin ? (float*)d_out : nullptr);
    hp = HB;
  }
}

// Round 10
// 43.611 us; speedup vs baseline: 1.2448x; 1.2448x over previous
//
#include <hip/hip_runtime.h>
#include <hip/hip_bf16.h>

#define NN 1024
#define DD 128
#define KK 16
#define CAP 128

typedef __attribute__((ext_vector_type(4))) float f32x4;
typedef __attribute__((ext_vector_type(8))) short bf16x8;
typedef __attribute__((ext_vector_type(4))) unsigned int u32x4;

static __device__ __forceinline__ unsigned short f2bf(float x) {
  union { __hip_bfloat16 h; unsigned short u; } v;
  v.h = __float2bfloat16(x);
  return v.u;
}
static __device__ __forceinline__ float bf2f(unsigned short u) {
  union { unsigned int ui; float f; } v;
  v.ui = ((unsigned int)u) << 16;
  return v.f;
}
static __device__ __forceinline__ unsigned int pack2(float a, float b) {
  return (unsigned int)f2bf(a) | ((unsigned int)f2bf(b) << 16);
}

// ---------------------------------------------------------------------------
// Kernel A: layer 0 WITH inline edge construction (one WG per node),
// plus 17 tail blocks producing W1B/W2B/wfT for layers 1-2.
// Per node-WG: r-table in LDS -> 2-pass ballot scan (emit nidx/edata16/cnt,
// nxs in LDS) -> r8-verified 64-row panel loop (Hs gathered from f32 embed,
// inline bf16 pack; As staged from just-written edata16, L1/L2-hot) ->
// r8-verified MLP with f32 weights (float2 pair loads) -> h1 f32 + hb16.
// ---------------------------------------------------------------------------
__global__ __launch_bounds__(256) void layer0_full(
    const float* __restrict__ r, const float* __restrict__ embed,
    const float* __restrict__ wfilt,          // [3][16][128] f32 (layer 0 slice used)
    const float* __restrict__ w1, const float* __restrict__ b1,
    const float* __restrict__ w2, const float* __restrict__ b2,
    int* __restrict__ cnt, int* __restrict__ nidx,
    unsigned short* __restrict__ edata16,
    unsigned short* __restrict__ w1ball, unsigned short* __restrict__ w2ball,
    unsigned short* __restrict__ wfT,
    float* __restrict__ hnext, unsigned short* __restrict__ hb16out)
{
  int b = blockIdx.x, tid = threadIdx.x;
  if (b >= NN) {
    if (b < NN + 16) {
      // cast w1,w2 (3 layers each: 49152 f32) -> bf16
      int gt = (b - NN) * 256 + tid;
      for (int f = gt; f < 98304; f += 4096) {
        if (f < 49152) w1ball[f]         = f2bf(w1[f]);
        else           w2ball[f - 49152] = f2bf(w2[f - 49152]);
      }
    } else {
      // wfT[l][d][kk]: transpose of wfilt[l][k][d], k zero-padded 16->32
      for (int e = tid; e < 3 * 128 * 32; e += 256) {
        int l = e >> 12, rem = e & 4095, dd = rem >> 5, kk = rem & 31;
        wfT[e] = (kk < KK) ? f2bf(wfilt[l * 2048 + kk * 128 + dd])
                           : (unsigned short)0;
      }
    }
    return;
  }

  __shared__ float Rs[NN][3];              // 12 KB
  __shared__ unsigned short Hs[64][136];   // 17.4 KB
  __shared__ unsigned short As[64][40];    // 5.1 KB
  __shared__ int   nxs[CAP];
  __shared__ int   wcnt[4], wbase[4], cn_sh;
  __shared__ float xv[128];
  __shared__ float yv[128];
  __shared__ float part4[4][128];

  int i = b;
  int w = tid >> 6, lane = tid & 63;
  int lg = lane >> 4, l16 = lane & 15;

  // ---- load r table ----
  #pragma unroll
  for (int it = 0; it < 3; ++it) {
    int idx = tid + it * 256;              // 768 f32x4 chunks
    ((f32x4*)Rs)[idx] = ((const f32x4*)r)[idx];
  }
  __syncthreads();

  float xi = Rs[i][0], yi = Rs[i][1], zi = Rs[i][2];

  // ---- pass 1: count (wave w owns j in [w*256, w*256+256)) ----
  int mycount = 0;
  #pragma unroll
  for (int it = 0; it < 4; ++it) {
    int j = w * 256 + it * 64 + lane;
    float dx = xi - Rs[j][0], dy = yi - Rs[j][1], dz = zi - Rs[j][2];
    float d2 = dx * dx + dy * dy + dz * dz;
    bool on = (j != i) && (d2 < 4.0f);
    mycount += (int)__popcll(__ballot(on));
  }
  if (lane == 0) wcnt[w] = mycount;
  __syncthreads();
  if (tid == 0) {
    int acc = 0;
    #pragma unroll
    for (int k = 0; k < 4; ++k) { wbase[k] = acc; acc += wcnt[k]; }
    cn_sh = (acc < CAP) ? acc : CAP;
  }
  __syncthreads();

  // ---- pass 2: emit ----
  {
    int base = wbase[w];
    #pragma unroll
    for (int it = 0; it < 4; ++it) {
      int j = w * 256 + it * 64 + lane;
      float dx = xi - Rs[j][0], dy = yi - Rs[j][1], dz = zi - Rs[j][2];
      float d2 = dx * dx + dy * dy + dz * dz;
      bool on = (j != i) && (d2 < 4.0f);
      unsigned long long mask = __ballot(on);
      int slot = base + (int)__popcll(mask & ((1ull << lane) - 1ull));
      if (on && slot < CAP) {
        float dist = sqrtf(d2);
        float ww = 0.5f * (__cosf(1.57079632679f * dist) + 1.0f);
        float E0 = __expf(-10.0f * d2);
        float q  = __expf(2.66666667f * dist);
        float u  = __expf(-0.17777778f);
        float u2 = u * u;
        float p = 1.0f, c = 1.0f, s = u;
        nxs[slot] = j;
        nidx[i * CAP + slot] = j;
        unsigned short* dst = edata16 + ((size_t)i * CAP + slot) * KK;
        #pragma unroll
        for (int k = 0; k < KK; ++k) {
          dst[k] = f2bf(ww * (E0 * p) * c);
          p *= q; c *= s; s *= u2;
        }
      }
      base += (int)__popcll(mask);
    }
  }
  if (tid == 0) cnt[i] = cn_sh;
  __threadfence_block();
  __syncthreads();
  int cn = cn_sh;

  // ---- B fragments from wfilt (layer 0) f32: k = lg*8+e valid only lg<2 ----
  bf16x8 bfr[2];
  #pragma unroll
  for (int nt = 0; nt < 2; ++nt) {
    int d = (w * 2 + nt) * 16 + l16;
    bf16x8 t = {0,0,0,0,0,0,0,0};
    if (lg < 2) {
      #pragma unroll
      for (int e = 0; e < 8; ++e)
        t[e] = (short)f2bf(wfilt[(lg * 8 + e) * 128 + d]);
    }
    bfr[nt] = t;
  }

  // ---- r8-verified panel loop ----
  float aggv0 = 0.f, aggv1 = 0.f;
  for (int p64 = 0; p64 < cn; p64 += 64) {
    int local_n = cn - p64; if (local_n > 64) local_n = 64;
    __syncthreads();
    #pragma unroll
    for (int it = 0; it < 4; ++it) {
      int c = tid + it * 256;
      int row = c >> 4, ch = c & 15;
      u32x4 v = {0u, 0u, 0u, 0u};
      if (row < local_n) {
        int j = nxs[p64 + row];
        const float* ep = embed + (size_t)j * DD + ch * 8;
        f32x4 ea = *(const f32x4*)(ep);
        f32x4 eb = *(const f32x4*)(ep + 4);
        v[0] = pack2(ea[0], ea[1]); v[1] = pack2(ea[2], ea[3]);
        v[2] = pack2(eb[0], eb[1]); v[3] = pack2(eb[2], eb[3]);
      }
      *(u32x4*)(&Hs[row][ch * 8]) = v;
    }
    {
      int row = tid >> 2, ch = tid & 3;
      u32x4 v = {0u, 0u, 0u, 0u};
      if (row < local_n && ch < 2)
        v = *(const u32x4*)(edata16 + ((size_t)i * CAP + p64 + row) * KK + ch * 8);
      *(u32x4*)(&As[row][ch * 8]) = v;
    }
    __syncthreads();

    bf16x8 af[4];
    #pragma unroll
    for (int mt = 0; mt < 4; ++mt)
      af[mt] = *(const bf16x8*)(&As[mt * 16 + l16][lg * 8]);
    f32x4 acc[4][2];
    #pragma unroll
    for (int mt = 0; mt < 4; ++mt)
      #pragma unroll
      for (int nt = 0; nt < 2; ++nt)
        acc[mt][nt] = (f32x4){0.f, 0.f, 0.f, 0.f};
    #pragma unroll
    for (int mt = 0; mt < 4; ++mt)
      #pragma unroll
      for (int nt = 0; nt < 2; ++nt)
        acc[mt][nt] = __builtin_amdgcn_mfma_f32_16x16x32_bf16(
            af[mt], bfr[nt], acc[mt][nt], 0, 0, 0);

    #pragma unroll
    for (int nt = 0; nt < 2; ++nt) {
      int d = (w * 2 + nt) * 16 + l16;
      float s = 0.f;
      #pragma unroll
      for (int mt = 0; mt < 4; ++mt)
        #pragma unroll
        for (int rr = 0; rr < 4; ++rr)
          s += acc[mt][nt][rr] * bf2f(Hs[mt * 16 + lg * 4 + rr][d]);
      if (nt == 0) aggv0 += s; else aggv1 += s;
    }
  }
  aggv0 += __shfl_xor(aggv0, 16, 64);
  aggv0 += __shfl_xor(aggv0, 32, 64);
  aggv1 += __shfl_xor(aggv1, 16, 64);
  aggv1 += __shfl_xor(aggv1, 32, 64);
  if (lg == 0) {
    xv[(w * 2 + 0) * 16 + l16] = aggv0;
    xv[(w * 2 + 1) * 16 + l16] = aggv1;
  }
  __syncthreads();

  // ---- MLP, f32 weights (layer 0 slices of w1/w2/b1/b2) ----
  int dp = tid & 63, pp = tid >> 6;
  float o1a = 0.f, o1b = 0.f;
  #pragma unroll 8
  for (int q = 0; q < 32; ++q) {
    int di = pp * 32 + q;
    float x = xv[di];
    float2 wp = *(const float2*)(w1 + di * DD + dp * 2);
    o1a += x * wp.x;
    o1b += x * wp.y;
  }
  part4[pp][dp * 2] = o1a;
  part4[pp][dp * 2 + 1] = o1b;
  __syncthreads();
  if (tid < 128) {
    float x = part4[0][tid] + part4[1][tid] + part4[2][tid] + part4[3][tid] + b1[tid];
    yv[tid] = x / (1.f + __expf(-x));
  }
  __syncthreads();
  float o2a = 0.f, o2b = 0.f;
  #pragma unroll 8
  for (int q = 0; q < 32; ++q) {
    int di = pp * 32 + q;
    float yy = yv[di];
    float2 wp = *(const float2*)(w2 + di * DD + dp * 2);
    o2a += yy * wp.x;
    o2b += yy * wp.y;
  }
  part4[pp][dp * 2] = o2a;
  part4[pp][dp * 2 + 1] = o2b;
  __syncthreads();
  if (tid < 128) {
    float v = part4[0][tid] + part4[1][tid] + part4[2][tid] + part4[3][tid]
              + b2[tid] + embed[(size_t)i * DD + tid];
    hnext[(size_t)i * DD + tid]   = v;
    hb16out[(size_t)i * DD + tid] = f2bf(v);
  }
}

// ---------------------------------------------------------------------------
// Kernel B (layers 1,2): r8-verified layer_fused, verbatim.
// ---------------------------------------------------------------------------
__global__ __launch_bounds__(256) void layer_fused(
    const int* __restrict__ cnt, const int* __restrict__ nidx,
    const unsigned short* __restrict__ edata16,
    const unsigned short* __restrict__ hb16in,
    const float* __restrict__ hprev,
    const unsigned short* __restrict__ wfTL,
    const unsigned short* __restrict__ w1b, const float* __restrict__ b1,
    const unsigned short* __restrict__ w2b, const float* __restrict__ b2,
    float* __restrict__ hnext,
    unsigned short* __restrict__ hb16out,
    float* __restrict__ outf)
{
  __shared__ unsigned short Hs[64][136];
  __shared__ unsigned short As[64][40];
  __shared__ int   nxs[CAP];
  __shared__ float xv[128];
  __shared__ float yv[128];
  __shared__ float part4[4][128];

  int i = blockIdx.x, tid = threadIdx.x;
  int w = tid >> 6, lane = tid & 63;
  int lg = lane >> 4, l16 = lane & 15;
  int cn = cnt[i];

  bf16x8 bfr[2];
  #pragma unroll
  for (int nt = 0; nt < 2; ++nt) {
    int d = (w * 2 + nt) * 16 + l16;
    bfr[nt] = *(const bf16x8*)(wfTL + d * 32 + lg * 8);
  }

  if (tid < CAP) nxs[tid] = nidx[i * CAP + tid];
  __syncthreads();

  float aggv0 = 0.f, aggv1 = 0.f;
  for (int p64 = 0; p64 < cn; p64 += 64) {
    int local_n = cn - p64; if (local_n > 64) local_n = 64;
    __syncthreads();
    #pragma unroll
    for (int it = 0; it < 4; ++it) {
      int c = tid + it * 256;
      int row = c >> 4, ch = c & 15;
      u32x4 v = {0u, 0u, 0u, 0u};
      if (row < local_n) {
        int j = nxs[p64 + row];
        v = *(const u32x4*)(hb16in + (size_t)j * DD + ch * 8);
      }
      *(u32x4*)(&Hs[row][ch * 8]) = v;
    }
    {
      int row = tid >> 2, ch = tid & 3;
      u32x4 v = {0u, 0u, 0u, 0u};
      if (row < local_n && ch < 2)
        v = *(const u32x4*)(edata16 + ((size_t)i * CAP + p64 + row) * KK + ch * 8);
      *(u32x4*)(&As[row][ch * 8]) = v;
    }
    __syncthreads();

    bf16x8 af[4];
    #pragma unroll
    for (int mt = 0; mt < 4; ++mt)
      af[mt] = *(const bf16x8*)(&As[mt * 16 + l16][lg * 8]);
    f32x4 acc[4][2];
    #pragma unroll
    for (int mt = 0; mt < 4; ++mt)
      #pragma unroll
      for (int nt = 0; nt < 2; ++nt)
        acc[mt][nt] = (f32x4){0.f, 0.f, 0.f, 0.f};
    #pragma unroll
    for (int mt = 0; mt < 4; ++mt)
      #pragma unroll
      for (int nt = 0; nt < 2; ++nt)
        acc[mt][nt] = __builtin_amdgcn_mfma_f32_16x16x32_bf16(
            af[mt], bfr[nt], acc[mt][nt], 0, 0, 0);

    #pragma unroll
    for (int nt = 0; nt < 2; ++nt) {
      int d = (w * 2 + nt) * 16 + l16;
      float s = 0.f;
      #pragma unroll
      for (int mt = 0; mt < 4; ++mt)
        #pragma unroll
        for (int rr = 0; rr < 4; ++rr)
          s += acc[mt][nt][rr] * bf2f(Hs[mt * 16 + lg * 4 + rr][d]);
      if (nt == 0) aggv0 += s; else aggv1 += s;
    }
  }
  aggv0 += __shfl_xor(aggv0, 16, 64);
  aggv0 += __shfl_xor(aggv0, 32, 64);
  aggv1 += __shfl_xor(aggv1, 16, 64);
  aggv1 += __shfl_xor(aggv1, 32, 64);
  if (lg == 0) {
    xv[(w * 2 + 0) * 16 + l16] = aggv0;
    xv[(w * 2 + 1) * 16 + l16] = aggv1;
  }
  __syncthreads();

  int dp = tid & 63, pp = tid >> 6;
  float o1a = 0.f, o1b = 0.f;
  #pragma unroll 8
  for (int q = 0; q < 32; ++q) {
    int di = pp * 32 + q;
    float x = xv[di];
    unsigned int wp = *(const unsigned int*)(w1b + di * DD + dp * 2);
    o1a += x * bf2f((unsigned short)(wp & 0xffffu));
    o1b += x * bf2f((unsigned short)(wp >> 16));
  }
  part4[pp][dp * 2] = o1a;
  part4[pp][dp * 2 + 1] = o1b;
  __syncthreads();
  if (tid < 128) {
    float x = part4[0][tid] + part4[1][tid] + part4[2][tid] + part4[3][tid] + b1[tid];
    yv[tid] = x / (1.f + __expf(-x));
  }
  __syncthreads();
  float o2a = 0.f, o2b = 0.f;
  #pragma unroll 8
  for (int q = 0; q < 32; ++q) {
    int di = pp * 32 + q;
    float yy = yv[di];
    unsigned int wp = *(const unsigned int*)(w2b + di * DD + dp * 2);
    o2a += yy * bf2f((unsigned short)(wp & 0xffffu));
    o2b += yy * bf2f((unsigned short)(wp >> 16));
  }
  part4[pp][dp * 2] = o2a;
  part4[pp][dp * 2 + 1] = o2b;
  __syncthreads();
  if (tid < 128) {
    float v = part4[0][tid] + part4[1][tid] + part4[2][tid] + part4[3][tid]
              + b2[tid] + hprev[(size_t)i * DD + tid];
    if (outf) {
      outf[(size_t)i * DD + tid] = v;
    } else {
      hnext[(size_t)i * DD + tid]   = v;
      hb16out[(size_t)i * DD + tid] = f2bf(v);
    }
  }
}

// ---------------------------------------------------------------------------
extern "C" void kernel_launch(void* const* d_in, const int* in_sizes, int n_in,
                              void* d_out, int out_size, void* d_ws, size_t ws_size,
                              hipStream_t stream) {
  (void)in_sizes; (void)n_in; (void)out_size; (void)ws_size;
  const float* r     = (const float*)d_in[0];
  const float* embed = (const float*)d_in[1];
  const float* wfilt = (const float*)d_in[2];
  const float* w1    = (const float*)d_in[3];
  const float* b1    = (const float*)d_in[4];
  const float* w2    = (const float*)d_in[5];
  const float* b2    = (const float*)d_in[6];

  char* ws = (char*)d_ws;
  size_t off = 0;
  auto alloc = [&](size_t bytes) {
    void* p = ws + off; off += (bytes + 255) & ~(size_t)255; return p;
  };
  unsigned short* EDATA = (unsigned short*)alloc((size_t)NN * CAP * KK * 2); // 4.2 MB
  int*            NIDX  = (int*)alloc((size_t)NN * CAP * 4);                 // 512 KB
  int*            CNT   = (int*)alloc((size_t)NN * 4);
  unsigned short* HB16A = (unsigned short*)alloc((size_t)NN * DD * 2);
  unsigned short* HB16B = (unsigned short*)alloc((size_t)NN * DD * 2);
  unsigned short* W1B   = (unsigned short*)alloc((size_t)3 * DD * DD * 2);
  unsigned short* W2B   = (unsigned short*)alloc((size_t)3 * DD * DD * 2);
  unsigned short* WFT   = (unsigned short*)alloc((size_t)3 * DD * 32 * 2);
  float*          HB    = (float*)alloc((size_t)NN * DD * 4);

  // Layer 0 + edge construction + weight-cast tail blocks (1 launch)
  layer0_full<<<NN + 17, 256, 0, stream>>>(
      r, embed, wfilt, w1, b1, w2, b2,
      CNT, NIDX, EDATA, W1B, W2B, WFT, HB, HB16B);

  // Layers 1, 2
  for (int l = 1; l < 3; ++l) {
    bool fin = (l == 2);
    const unsigned short* in16  = (l == 1) ? HB16B : HB16A;
    unsigned short*       out16 = (l == 1) ? HB16A : HB16B;
    layer_fused<<<NN, 256, 0, stream>>>(
        CNT, NIDX, EDATA, in16, HB,
        WFT + (size_t)l * DD * 32,
        W1B + (size_t)l * DD * DD, b1 + (size_t)l * DD,
        W2B + (size_t)l * DD * DD, b2 + (size_t)l * DD,
        fin ? nullptr : HB, fin ? nullptr : out16,
        fin ? (float*)d_out : nullptr);
  }
}

// Round 11
// 42.740 us; speedup vs baseline: 1.2702x; 1.0204x over previous
//
#include <hip/hip_runtime.h>
#include <hip/hip_bf16.h>

#define NN 1024
#define DD 128
#define KK 16
#define CAP 128

typedef __attribute__((ext_vector_type(4))) float f32x4;
typedef __attribute__((ext_vector_type(8))) short bf16x8;
typedef __attribute__((ext_vector_type(4))) unsigned int u32x4;

static __device__ __forceinline__ unsigned short f2bf(float x) {
  union { __hip_bfloat16 h; unsigned short u; } v;
  v.h = __float2bfloat16(x);
  return v.u;
}
static __device__ __forceinline__ float bf2f(unsigned short u) {
  union { unsigned int ui; float f; } v;
  v.ui = ((unsigned int)u) << 16;
  return v.f;
}
static __device__ __forceinline__ unsigned int pack2(float a, float b) {
  return (unsigned int)f2bf(a) | ((unsigned int)f2bf(b) << 16);
}

// RBF row chunk: 4 bf16 pairs (k8..k8+7) packed into u32x4, from dist
static __device__ __forceinline__ u32x4 rbf8(float dist, int k8) {
  float ww = 0.5f * (__cosf(1.57079632679f * dist) + 1.0f);
  u32x4 v;
  #pragma unroll
  for (int e = 0; e < 4; ++e) {
    float mu0 = (float)(k8 + 2 * e) * (2.0f / 15.0f);
    float mu1 = (float)(k8 + 2 * e + 1) * (2.0f / 15.0f);
    float d0 = dist - mu0, d1 = dist - mu1;
    v[e] = pack2(ww * __expf(-10.f * d0 * d0), ww * __expf(-10.f * d1 * d1));
  }
  return v;
}

// ---------------------------------------------------------------------------
// Kernel A: layer 0 WITH inline edge construction (one WG per node),
// plus 17 tail blocks producing W1B/W2B/wfT for layers 1-2.
// Edge data stored as dist f32 only; RBF recomputed inline at As staging.
// ---------------------------------------------------------------------------
__global__ __launch_bounds__(256) void layer0_full(
    const float* __restrict__ r, const float* __restrict__ embed,
    const float* __restrict__ wfilt,          // [3][16][128] f32
    const float* __restrict__ w1, const float* __restrict__ b1,
    const float* __restrict__ w2, const float* __restrict__ b2,
    int* __restrict__ cnt, int* __restrict__ nidx,
    float* __restrict__ distg,
    unsigned short* __restrict__ w1ball, unsigned short* __restrict__ w2ball,
    unsigned short* __restrict__ wfT,
    float* __restrict__ hnext, unsigned short* __restrict__ hb16out)
{
  int b = blockIdx.x, tid = threadIdx.x;
  if (b >= NN) {
    if (b < NN + 16) {
      int gt = (b - NN) * 256 + tid;
      for (int f = gt; f < 98304; f += 4096) {
        if (f < 49152) w1ball[f]         = f2bf(w1[f]);
        else           w2ball[f - 49152] = f2bf(w2[f - 49152]);
      }
    } else {
      for (int e = tid; e < 3 * 128 * 32; e += 256) {
        int l = e >> 12, rem = e & 4095, dd = rem >> 5, kk = rem & 31;
        wfT[e] = (kk < KK) ? f2bf(wfilt[l * 2048 + kk * 128 + dd])
                           : (unsigned short)0;
      }
    }
    return;
  }

  __shared__ float Rs[NN][3];              // 12 KB
  __shared__ unsigned short Hs[64][136];   // 17.4 KB
  __shared__ unsigned short As[64][40];    // 5.1 KB
  __shared__ int   nxs[CAP];
  __shared__ float dsts[CAP];
  __shared__ int   wcnt[4], wbase[4], cn_sh;
  __shared__ float xv[128];
  __shared__ float yv[128];
  __shared__ float part4[4][128];

  int i = b;
  int w = tid >> 6, lane = tid & 63;
  int lg = lane >> 4, l16 = lane & 15;

  #pragma unroll
  for (int it = 0; it < 3; ++it) {
    int idx = tid + it * 256;
    ((f32x4*)Rs)[idx] = ((const f32x4*)r)[idx];
  }
  __syncthreads();

  float xi = Rs[i][0], yi = Rs[i][1], zi = Rs[i][2];

  // ---- pass 1: count ----
  int mycount = 0;
  #pragma unroll
  for (int it = 0; it < 4; ++it) {
    int j = w * 256 + it * 64 + lane;
    float dx = xi - Rs[j][0], dy = yi - Rs[j][1], dz = zi - Rs[j][2];
    float d2 = dx * dx + dy * dy + dz * dz;
    bool on = (j != i) && (d2 < 4.0f);
    mycount += (int)__popcll(__ballot(on));
  }
  if (lane == 0) wcnt[w] = mycount;
  __syncthreads();
  if (tid == 0) {
    int acc = 0;
    #pragma unroll
    for (int k = 0; k < 4; ++k) { wbase[k] = acc; acc += wcnt[k]; }
    cn_sh = (acc < CAP) ? acc : CAP;
  }
  __syncthreads();

  // ---- pass 2: emit (nidx + dist only) ----
  {
    int base = wbase[w];
    #pragma unroll
    for (int it = 0; it < 4; ++it) {
      int j = w * 256 + it * 64 + lane;
      float dx = xi - Rs[j][0], dy = yi - Rs[j][1], dz = zi - Rs[j][2];
      float d2 = dx * dx + dy * dy + dz * dz;
      bool on = (j != i) && (d2 < 4.0f);
      unsigned long long mask = __ballot(on);
      int slot = base + (int)__popcll(mask & ((1ull << lane) - 1ull));
      if (on && slot < CAP) {
        float dist = sqrtf(d2);
        nxs[slot]  = j;
        dsts[slot] = dist;
        nidx[i * CAP + slot]  = j;
        distg[i * CAP + slot] = dist;
      }
      base += (int)__popcll(mask);
    }
  }
  if (tid == 0) cnt[i] = cn_sh;
  __syncthreads();
  int cn = cn_sh;

  // ---- B fragments from wfilt (layer 0) f32 ----
  bf16x8 bfr[2];
  #pragma unroll
  for (int nt = 0; nt < 2; ++nt) {
    int d = (w * 2 + nt) * 16 + l16;
    bf16x8 t = {0,0,0,0,0,0,0,0};
    if (lg < 2) {
      #pragma unroll
      for (int e = 0; e < 8; ++e)
        t[e] = (short)f2bf(wfilt[(lg * 8 + e) * 128 + d]);
    }
    bfr[nt] = t;
  }

  // ---- panel loop (r10-verified; As from inline RBF) ----
  float aggv0 = 0.f, aggv1 = 0.f;
  for (int p64 = 0; p64 < cn; p64 += 64) {
    int local_n = cn - p64; if (local_n > 64) local_n = 64;
    __syncthreads();
    #pragma unroll
    for (int it = 0; it < 4; ++it) {
      int c = tid + it * 256;
      int row = c >> 4, ch = c & 15;
      u32x4 v = {0u, 0u, 0u, 0u};
      if (row < local_n) {
        int j = nxs[p64 + row];
        const float* ep = embed + (size_t)j * DD + ch * 8;
        f32x4 ea = *(const f32x4*)(ep);
        f32x4 eb = *(const f32x4*)(ep + 4);
        v[0] = pack2(ea[0], ea[1]); v[1] = pack2(ea[2], ea[3]);
        v[2] = pack2(eb[0], eb[1]); v[3] = pack2(eb[2], eb[3]);
      }
      *(u32x4*)(&Hs[row][ch * 8]) = v;
    }
    {
      int row = tid >> 2, q = tid & 3;
      u32x4 v = {0u, 0u, 0u, 0u};
      if (row < local_n && q < 2)
        v = rbf8(dsts[p64 + row], q * 8);
      *(u32x4*)(&As[row][q * 8]) = v;
    }
    __syncthreads();

    bf16x8 af[4];
    #pragma unroll
    for (int mt = 0; mt < 4; ++mt)
      af[mt] = *(const bf16x8*)(&As[mt * 16 + l16][lg * 8]);
    f32x4 acc[4][2];
    #pragma unroll
    for (int mt = 0; mt < 4; ++mt)
      #pragma unroll
      for (int nt = 0; nt < 2; ++nt)
        acc[mt][nt] = (f32x4){0.f, 0.f, 0.f, 0.f};
    #pragma unroll
    for (int mt = 0; mt < 4; ++mt)
      #pragma unroll
      for (int nt = 0; nt < 2; ++nt)
        acc[mt][nt] = __builtin_amdgcn_mfma_f32_16x16x32_bf16(
            af[mt], bfr[nt], acc[mt][nt], 0, 0, 0);

    #pragma unroll
    for (int nt = 0; nt < 2; ++nt) {
      int d = (w * 2 + nt) * 16 + l16;
      float s = 0.f;
      #pragma unroll
      for (int mt = 0; mt < 4; ++mt)
        #pragma unroll
        for (int rr = 0; rr < 4; ++rr)
          s += acc[mt][nt][rr] * bf2f(Hs[mt * 16 + lg * 4 + rr][d]);
      if (nt == 0) aggv0 += s; else aggv1 += s;
    }
  }
  aggv0 += __shfl_xor(aggv0, 16, 64);
  aggv0 += __shfl_xor(aggv0, 32, 64);
  aggv1 += __shfl_xor(aggv1, 16, 64);
  aggv1 += __shfl_xor(aggv1, 32, 64);
  if (lg == 0) {
    xv[(w * 2 + 0) * 16 + l16] = aggv0;
    xv[(w * 2 + 1) * 16 + l16] = aggv1;
  }
  __syncthreads();

  // ---- MLP, f32 weights (layer 0) ----
  int dp = tid & 63, pp = tid >> 6;
  float o1a = 0.f, o1b = 0.f;
  #pragma unroll 8
  for (int q = 0; q < 32; ++q) {
    int di = pp * 32 + q;
    float x = xv[di];
    float2 wp = *(const float2*)(w1 + di * DD + dp * 2);
    o1a += x * wp.x;
    o1b += x * wp.y;
  }
  part4[pp][dp * 2] = o1a;
  part4[pp][dp * 2 + 1] = o1b;
  __syncthreads();
  if (tid < 128) {
    float x = part4[0][tid] + part4[1][tid] + part4[2][tid] + part4[3][tid] + b1[tid];
    yv[tid] = x / (1.f + __expf(-x));
  }
  __syncthreads();
  float o2a = 0.f, o2b = 0.f;
  #pragma unroll 8
  for (int q = 0; q < 32; ++q) {
    int di = pp * 32 + q;
    float yy = yv[di];
    float2 wp = *(const float2*)(w2 + di * DD + dp * 2);
    o2a += yy * wp.x;
    o2b += yy * wp.y;
  }
  part4[pp][dp * 2] = o2a;
  part4[pp][dp * 2 + 1] = o2b;
  __syncthreads();
  if (tid < 128) {
    float v = part4[0][tid] + part4[1][tid] + part4[2][tid] + part4[3][tid]
              + b2[tid] + embed[(size_t)i * DD + tid];
    hnext[(size_t)i * DD + tid]   = v;
    hb16out[(size_t)i * DD + tid] = f2bf(v);
  }
}

// ---------------------------------------------------------------------------
// Kernel B (layers 1,2): r10-verified body; As from inline RBF (dist in LDS).
// ---------------------------------------------------------------------------
__global__ __launch_bounds__(256) void layer_fused(
    const int* __restrict__ cnt, const int* __restrict__ nidx,
    const float* __restrict__ distg,
    const unsigned short* __restrict__ hb16in,
    const float* __restrict__ hprev,
    const unsigned short* __restrict__ wfTL,
    const unsigned short* __restrict__ w1b, const float* __restrict__ b1,
    const unsigned short* __restrict__ w2b, const float* __restrict__ b2,
    float* __restrict__ hnext,
    unsigned short* __restrict__ hb16out,
    float* __restrict__ outf)
{
  __shared__ unsigned short Hs[64][136];
  __shared__ unsigned short As[64][40];
  __shared__ int   nxs[CAP];
  __shared__ float dsts[CAP];
  __shared__ float xv[128];
  __shared__ float yv[128];
  __shared__ float part4[4][128];

  int i = blockIdx.x, tid = threadIdx.x;
  int w = tid >> 6, lane = tid & 63;
  int lg = lane >> 4, l16 = lane & 15;
  int cn = cnt[i];

  if (tid < CAP) {
    nxs[tid]  = nidx[i * CAP + tid];
    dsts[tid] = distg[i * CAP + tid];
  }

  bf16x8 bfr[2];
  #pragma unroll
  for (int nt = 0; nt < 2; ++nt) {
    int d = (w * 2 + nt) * 16 + l16;
    bfr[nt] = *(const bf16x8*)(wfTL + d * 32 + lg * 8);
  }
  __syncthreads();

  float aggv0 = 0.f, aggv1 = 0.f;
  for (int p64 = 0; p64 < cn; p64 += 64) {
    int local_n = cn - p64; if (local_n > 64) local_n = 64;
    __syncthreads();
    #pragma unroll
    for (int it = 0; it < 4; ++it) {
      int c = tid + it * 256;
      int row = c >> 4, ch = c & 15;
      u32x4 v = {0u, 0u, 0u, 0u};
      if (row < local_n) {
        int j = nxs[p64 + row];
        v = *(const u32x4*)(hb16in + (size_t)j * DD + ch * 8);
      }
      *(u32x4*)(&Hs[row][ch * 8]) = v;
    }
    {
      int row = tid >> 2, q = tid & 3;
      u32x4 v = {0u, 0u, 0u, 0u};
      if (row < local_n && q < 2)
        v = rbf8(dsts[p64 + row], q * 8);
      *(u32x4*)(&As[row][q * 8]) = v;
    }
    __syncthreads();

    bf16x8 af[4];
    #pragma unroll
    for (int mt = 0; mt < 4; ++mt)
      af[mt] = *(const bf16x8*)(&As[mt * 16 + l16][lg * 8]);
    f32x4 acc[4][2];
    #pragma unroll
    for (int mt = 0; mt < 4; ++mt)
      #pragma unroll
      for (int nt = 0; nt < 2; ++nt)
        acc[mt][nt] = (f32x4){0.f, 0.f, 0.f, 0.f};
    #pragma unroll
    for (int mt = 0; mt < 4; ++mt)
      #pragma unroll
      for (int nt = 0; nt < 2; ++nt)
        acc[mt][nt] = __builtin_amdgcn_mfma_f32_16x16x32_bf16(
            af[mt], bfr[nt], acc[mt][nt], 0, 0, 0);

    #pragma unroll
    for (int nt = 0; nt < 2; ++nt) {
      int d = (w * 2 + nt) * 16 + l16;
      float s = 0.f;
      #pragma unroll
      for (int mt = 0; mt < 4; ++mt)
        #pragma unroll
        for (int rr = 0; rr < 4; ++rr)
          s += acc[mt][nt][rr] * bf2f(Hs[mt * 16 + lg * 4 + rr][d]);
      if (nt == 0) aggv0 += s; else aggv1 += s;
    }
  }
  aggv0 += __shfl_xor(aggv0, 16, 64);
  aggv0 += __shfl_xor(aggv0, 32, 64);
  aggv1 += __shfl_xor(aggv1, 16, 64);
  aggv1 += __shfl_xor(aggv1, 32, 64);
  if (lg == 0) {
    xv[(w * 2 + 0) * 16 + l16] = aggv0;
    xv[(w * 2 + 1) * 16 + l16] = aggv1;
  }
  __syncthreads();

  int dp = tid & 63, pp = tid >> 6;
  float o1a = 0.f, o1b = 0.f;
  #pragma unroll 8
  for (int q = 0; q < 32; ++q) {
    int di = pp * 32 + q;
    float x = xv[di];
    unsigned int wp = *(const unsigned int*)(w1b + di * DD + dp * 2);
    o1a += x * bf2f((unsigned short)(wp & 0xffffu));
    o1b += x * bf2f((unsigned short)(wp >> 16));
  }
  part4[pp][dp * 2] = o1a;
  part4[pp][dp * 2 + 1] = o1b;
  __syncthreads();
  if (tid < 128) {
    float x = part4[0][tid] + part4[1][tid] + part4[2][tid] + part4[3][tid] + b1[tid];
    yv[tid] = x / (1.f + __expf(-x));
  }
  __syncthreads();
  float o2a = 0.f, o2b = 0.f;
  #pragma unroll 8
  for (int q = 0; q < 32; ++q) {
    int di = pp * 32 + q;
    float yy = yv[di];
    unsigned int wp = *(const unsigned int*)(w2b + di * DD + dp * 2);
    o2a += yy * bf2f((unsigned short)(wp & 0xffffu));
    o2b += yy * bf2f((unsigned short)(wp >> 16));
  }
  part4[pp][dp * 2] = o2a;
  part4[pp][dp * 2 + 1] = o2b;
  __syncthreads();
  if (tid < 128) {
    float v = part4[0][tid] + part4[1][tid] + part4[2][tid] + part4[3][tid]
              + b2[tid] + hprev[(size_t)i * DD + tid];
    if (outf) {
      outf[(size_t)i * DD + tid] = v;
    } else {
      hnext[(size_t)i * DD + tid]   = v;
      hb16out[(size_t)i * DD + tid] = f2bf(v);
    }
  }
}

// ---------------------------------------------------------------------------
extern "C" void kernel_launch(void* const* d_in, const int* in_sizes, int n_in,
                              void* d_out, int out_size, void* d_ws, size_t ws_size,
                              hipStream_t stream) {
  (void)in_sizes; (void)n_in; (void)out_size; (void)ws_size;
  const float* r     = (const float*)d_in[0];
  const float* embed = (const float*)d_in[1];
  const float* wfilt = (const float*)d_in[2];
  const float* w1    = (const float*)d_in[3];
  const float* b1    = (const float*)d_in[4];
  const float* w2    = (const float*)d_in[5];
  const float* b2    = (const float*)d_in[6];

  char* ws = (char*)d_ws;
  size_t off = 0;
  auto alloc = [&](size_t bytes) {
    void* p = ws + off; off += (bytes + 255) & ~(size_t)255; return p;
  };
  float*          DIST  = (float*)alloc((size_t)NN * CAP * 4);          // 512 KB
  int*            NIDX  = (int*)alloc((size_t)NN * CAP * 4);            // 512 KB
  int*            CNT   = (int*)alloc((size_t)NN * 4);
  unsigned short* HB16A = (unsigned short*)alloc((size_t)NN * DD * 2);
  unsigned short* HB16B = (unsigned short*)alloc((size_t)NN * DD * 2);
  unsigned short* W1B   = (unsigned short*)alloc((size_t)3 * DD * DD * 2);
  unsigned short* W2B   = (unsigned short*)alloc((size_t)3 * DD * DD * 2);
  unsigned short* WFT   = (unsigned short*)alloc((size_t)3 * DD * 32 * 2);
  float*          HB    = (float*)alloc((size_t)NN * DD * 4);

  layer0_full<<<NN + 17, 256, 0, stream>>>(
      r, embed, wfilt, w1, b1, w2, b2,
      CNT, NIDX, DIST, W1B, W2B, WFT, HB, HB16B);

  for (int l = 1; l < 3; ++l) {
    bool fin = (l == 2);
    const unsigned short* in16  = (l == 1) ? HB16B : HB16A;
    unsigned short*       out16 = (l == 1) ? HB16A : HB16B;
    layer_fused<<<NN, 256, 0, stream>>>(
        CNT, NIDX, DIST, in16, HB,
        WFT + (size_t)l * DD * 32,
        W1B + (size_t)l * DD * DD, b1 + (size_t)l * DD,
        W2B + (size_t)l * DD * DD, b2 + (size_t)l * DD,
        fin ? nullptr : HB, fin ? nullptr : out16,
        fin ? (float*)d_out : nullptr);
  }
}